// Round 7
// baseline (1429.152 us; speedup 1.0000x reference)
//
#include <hip/hip_runtime.h>
#include <hip/hip_bf16.h>

// ---------------------------------------------------------------------------
// FCx2DetHead pipeline. R14: mega-kernel with HAND-ROLLED grid barrier.
// R13's cg::grid_group::sync() raced (absmax 9e-4 direct) and broke under
// graph capture (garbage in bench). Same fused structure, but:
//  - plain <<<512,256>>> launch, __launch_bounds__(256,2) -> VGPR<=256 ->
//    2 blocks/CU by regs (LDS 48KB allows 3) -> all 512 blocks co-resident.
//  - hierarchical barrier: 8 group counters (64 arrivals) -> root (8) ->
//    gen bump; agent-scope scoped atomics (acq/rel emit L2 wb/inv) +
//    __threadfence at tid0. ~1us/barrier vs ~15us for flat 512-way atomic.
//  - barrier state in ws, hipMemsetAsync-reset each launch (capture-safe).
//  - bounded spin: fails loud (wrong absmax) instead of hanging.
// Stage code byte-identical to verified R12 kernels.
// ---------------------------------------------------------------------------

#define NROI 256
#define NB   8
#define INF  12544   // 256*49
#define DFC  1024
#define FCC  512
#define NBLK 512
#define NTHR 256
#define NGRP 8
#define GRPSZ (NBLK / NGRP)

typedef __attribute__((ext_vector_type(8))) short short8;
typedef __attribute__((ext_vector_type(4))) float floatx4;

static __device__ __forceinline__ unsigned short f2bf(float f) {
    unsigned int u = __float_as_uint(f);
    unsigned int r = (u + 0x7fffu + ((u >> 16) & 1u)) >> 16;
    return (unsigned short)r;
}

static __device__ __forceinline__ void async_copy16(const void* g, void* l) {
    __builtin_amdgcn_global_load_lds(
        (const __attribute__((address_space(1))) unsigned int*)g,
        (__attribute__((address_space(3))) unsigned int*)l, 16, 0, 0);
}

// ---------------- grid barrier (bar[0..7]=grp, bar[8]=root, bar[9]=gen) -----
static __device__ __forceinline__ void gbar(unsigned* bar, int bid, int tid) {
    __syncthreads();
    if (tid == 0) {
        __threadfence();
        unsigned* grp  = bar + (bid >> 6);
        unsigned* root = bar + NGRP;
        unsigned* gen  = bar + NGRP + 1;
        unsigned g = __hip_atomic_load(gen, __ATOMIC_ACQUIRE, __HIP_MEMORY_SCOPE_AGENT);
        unsigned a = __hip_atomic_fetch_add(grp, 1u, __ATOMIC_ACQ_REL, __HIP_MEMORY_SCOPE_AGENT);
        if (a == GRPSZ - 1) {
            __hip_atomic_store(grp, 0u, __ATOMIC_RELAXED, __HIP_MEMORY_SCOPE_AGENT);
            unsigned r = __hip_atomic_fetch_add(root, 1u, __ATOMIC_ACQ_REL, __HIP_MEMORY_SCOPE_AGENT);
            if (r == NGRP - 1) {
                __hip_atomic_store(root, 0u, __ATOMIC_RELAXED, __HIP_MEMORY_SCOPE_AGENT);
                __hip_atomic_store(gen, g + 1u, __ATOMIC_RELEASE, __HIP_MEMORY_SCOPE_AGENT);
            } else {
                for (int it = 0; it < 5000000; ++it) {
                    if (__hip_atomic_load(gen, __ATOMIC_ACQUIRE, __HIP_MEMORY_SCOPE_AGENT) != g) break;
                    __builtin_amdgcn_s_sleep(2);
                }
            }
        } else {
            for (int it = 0; it < 5000000; ++it) {
                if (__hip_atomic_load(gen, __ATOMIC_ACQUIRE, __HIP_MEMORY_SCOPE_AGENT) != g) break;
                __builtin_amdgcn_s_sleep(2);
            }
        }
        __threadfence();
    }
    __syncthreads();
}

// ---------------- transpose x (B,C,H,W) -> feat (B,H,W,C), one virt block ---
static __device__ __forceinline__ void transpose_it(char* smem, int tid, int f,
        const float* __restrict__ x, float* __restrict__ xT) {
    float (*t)[33] = (float(*)[33])smem;
    int xb = f % 20, yb = (f / 20) & 7, b = f / 160;
    int cb = yb * 32, lb = xb * 32;
    int tx = tid & 31, ty = tid >> 5;
#pragma unroll
    for (int r = 0; r < 4; ++r) {
        int c = cb + ty + r * 8, l = lb + tx;
        if (l < 625) t[ty + r * 8][tx] = x[(size_t)(b * 256 + c) * 625 + l];
    }
    __syncthreads();
#pragma unroll
    for (int r = 0; r < 4; ++r) {
        int l = lb + ty + r * 8, c = cb + tx;
        if (l < 625) xT[((size_t)b * 625 + l) * 256 + c] = t[tx][ty + r * 8];
    }
}

// ---------------- fused deformable RoI pool (prep + gather) -----------------
static __device__ void pool_stage(char* smem, int tid, int q, int n,
        const float* __restrict__ feat, const float* __restrict__ rois,
        const float* __restrict__ off, int has_off,
        unsigned short* __restrict__ P) {
    float (*sGrid)[16] = (float(*)[16])smem;                 // 3136 B
    int* sBase = (int*)(smem + 3136);                        // 196 B
    unsigned short* sOut = (unsigned short*)(smem + 3584);   // 12544 B
    const float SSC = (float)(25.0 / 255.0);

    if (tid < 49) {
        int bin = tid;
        const float* r = rois + n * 5;
        int b = (int)r[0];
        float sw = rintf(r[1]) * SSC - 0.5f;
        float sh = rintf(r[2]) * SSC - 0.5f;
        float rw = fmaxf((rintf(r[3]) + 1.0f) * SSC - 0.5f - sw, 0.1f);
        float rh = fmaxf((rintf(r[4]) + 1.0f) * SSC - 0.5f - sh, 0.1f);
        float bw = rw / 7.0f, bh = rh / 7.0f;
        float bws = bw * 0.25f, bhs = bh * 0.25f;
        int ph = bin / 7, pw = bin - ph * 7;
        float tx = 0.f, ty = 0.f;
        if (has_off) {
            tx = off[n * 98 + bin] * 0.1f;
            ty = off[n * 98 + 49 + bin] * 0.1f;
        }
        float wstart = pw * bw + sw + tx * rw;
        float hstart = ph * bh + sh + ty * rh;
#pragma unroll
        for (int i = 0; i < 16; ++i) sGrid[bin][i] = 0.f;
        int gy0 = 0, gx0 = 0, cnt = 0;
#pragma unroll
        for (int s = 0; s < 16; ++s) {
            float fx = wstart + (s & 3) * bws;
            float fy = hstart + (s >> 2) * bhs;
            bool valid = (fx >= -0.5f) && (fx <= 24.5f) && (fy >= -0.5f) && (fy <= 24.5f);
            float xc = fminf(fmaxf(fx, 0.f), 24.f);
            float yc = fminf(fmaxf(fy, 0.f), 24.f);
            float x0f = floorf(xc), y0f = floorf(yc);
            float dx = xc - x0f, dy = yc - y0f;
            int x0 = (int)x0f, y0 = (int)y0f;
            int x1 = (int)ceilf(xc), y1 = (int)ceilf(yc);
            if (s == 0) { gy0 = y0; gx0 = x0; }
            float w00 = (1.f - dx) * (1.f - dy), w01 = dx * (1.f - dy);
            float w10 = (1.f - dx) * dy,         w11 = dx * dy;
            if (!valid) { w00 = w01 = w10 = w11 = 0.f; }
            cnt += valid ? 1 : 0;
            int ry0 = (y0 - gy0) * 4, ry1 = (y1 - gy0) * 4;
            sGrid[bin][ry0 + (x0 - gx0)] += w00;
            sGrid[bin][ry0 + (x1 - gx0)] += w01;
            sGrid[bin][ry1 + (x0 - gx0)] += w10;
            sGrid[bin][ry1 + (x1 - gx0)] += w11;
        }
        float inv = 1.0f / fmaxf((float)cnt, 1.0f);
#pragma unroll
        for (int i = 0; i < 16; ++i) sGrid[bin][i] *= inv;
        sBase[bin] = gy0 | (gx0 << 8) | (b << 16);
    }
    __syncthreads();

    int wv = tid >> 6, lane = tid & 63;
    int cbase = q * 128 + lane * 2;
    for (int bin = wv; bin < 49; bin += 4) {
        int base = sBase[bin];
        int gy0 = base & 255, gx0 = (base >> 8) & 255, b = base >> 16;
        const float4* wp = (const float4*)sGrid[bin];
        float4 w0 = wp[0], w1 = wp[1], w2 = wp[2], w3 = wp[3];
        float ww[16] = { w0.x, w0.y, w0.z, w0.w, w1.x, w1.y, w1.z, w1.w,
                         w2.x, w2.y, w2.z, w2.w, w3.x, w3.y, w3.z, w3.w };
        int rowOff[4], colOff[4];
#pragma unroll
        for (int r = 0; r < 4; ++r) {
            rowOff[r] = min(gy0 + r, 24) * 25;
            colOff[r] = min(gx0 + r, 24);
        }
        int b625 = b * 625;
        float ax = 0.f, ay = 0.f;
#pragma unroll
        for (int cell = 0; cell < 16; ++cell) {
            int pix = b625 + rowOff[cell >> 2] + colOff[cell & 3];
            float2 v = *(const float2*)(feat + (size_t)pix * 256 + cbase);
            ax += ww[cell] * v.x;
            ay += ww[cell] * v.y;
        }
        sOut[(lane * 2) * 49 + bin] = f2bf(ax);
        sOut[(lane * 2 + 1) * 49 + bin] = f2bf(ay);
    }
    __syncthreads();
    const uint2* so = (const uint2*)sOut;
    uint2* dp = (uint2*)(P + (size_t)n * INF + q * 128 * 49);
    for (int i = tid; i < 128 * 49 / 4; i += 256) dp[i] = so[i];
}

// ---------------- 2-phase MFMA GEMM (BM=256=M, BN=64) -> fp32 partials ------
static __device__ void gemm_stage(char* smem, int tid,
        const unsigned short* __restrict__ A, const float* __restrict__ Bw,
        float* __restrict__ Cpart, int N, int K, int kSteps, int nb, int z) {
    constexpr int BM = 256, BN = 64;
    constexpr int FM = 4, FN = 4;
    unsigned short* AsB = (unsigned short*)smem;      // 2 slots x 8192 shorts
    float* BsB = (float*)(smem + 32768);              // 2 slots x 2048 floats
    const int lane = tid & 63;
    const int wave = tid >> 6;
    const int n0 = nb * BN;
    const int k0 = z * kSteps * 32;
    const int quad = lane >> 4;
    const int l16 = lane & 15;

    floatx4 acc[FM][FN];
#pragma unroll
    for (int i = 0; i < FM; ++i)
#pragma unroll
        for (int j = 0; j < FN; ++j) acc[i][j] = (floatx4)0.f;

    const unsigned short* ag[4];
    int albase[4];
#pragma unroll
    for (int i = 0; i < 4; ++i) {
        int idx = tid + i * 256;
        int row = idx >> 2;
        int kg4 = (idx & 3) ^ ((row >> 1) & 3);
        ag[i] = A + (size_t)row * K + kg4 * 8;
        albase[i] = (i * 256 + wave * 64) * 16;   // wave-uniform byte base
    }
    const float* bg[2];
    int blbase[2];
#pragma unroll
    for (int i = 0; i < 2; ++i) {
        int idx = tid + i * 256;
        int row = idx >> 3;
        int kg = (idx & 7) ^ ((row >> 1) & 7);
        bg[i] = Bw + (size_t)(n0 + row) * K + kg * 4;
        blbase[i] = (i * 256 + wave * 64) * 16;
    }

    auto issue = [&](int slot, int kk) {
#pragma unroll
        for (int i = 0; i < 4; ++i)
            async_copy16(ag[i] + kk, smem + slot * 16384 + albase[i]);
#pragma unroll
        for (int i = 0; i < 2; ++i)
            async_copy16(bg[i] + kk, smem + 32768 + slot * 8192 + blbase[i]);
    };

    issue(0, k0);
    __syncthreads();

    int cur = 0;
    for (int ks = 0; ks < kSteps; ++ks) {
        if (ks + 1 < kSteps) issue(cur ^ 1, k0 + (ks + 1) * 32);
        short8 a[FM], bf[FN];
        const unsigned short* Asc = AsB + cur * 8192;
        const float* Bsc = BsB + cur * 2048;
#pragma unroll
        for (int i = 0; i < FM; ++i) {
            int r = wave * 64 + i * 16 + l16;
            int sl = quad ^ ((r >> 1) & 3);
            a[i] = *(const short8*)(Asc + r * 32 + sl * 8);
        }
#pragma unroll
        for (int j = 0; j < FN; ++j) {
            int r = j * 16 + l16;
            int sw8 = (r >> 1) & 7;
            int g0 = (quad * 2) ^ sw8;
            int g1 = (quad * 2 + 1) ^ sw8;
            float4 v0 = *(const float4*)(Bsc + r * 32 + g0 * 4);
            float4 v1 = *(const float4*)(Bsc + r * 32 + g1 * 4);
            bf[j][0] = (short)f2bf(v0.x); bf[j][1] = (short)f2bf(v0.y);
            bf[j][2] = (short)f2bf(v0.z); bf[j][3] = (short)f2bf(v0.w);
            bf[j][4] = (short)f2bf(v1.x); bf[j][5] = (short)f2bf(v1.y);
            bf[j][6] = (short)f2bf(v1.z); bf[j][7] = (short)f2bf(v1.w);
        }
#pragma unroll
        for (int i = 0; i < FM; ++i)
#pragma unroll
            for (int j = 0; j < FN; ++j)
                acc[i][j] = __builtin_amdgcn_mfma_f32_16x16x32_bf16(a[i], bf[j], acc[i][j], 0, 0, 0);
        __syncthreads();
        cur ^= 1;
    }
    float* Cp = Cpart + (size_t)z * BM * N;
#pragma unroll
    for (int i = 0; i < FM; ++i)
#pragma unroll
        for (int rr = 0; rr < 4; ++rr) {
            int row = wave * 64 + i * 16 + quad * 4 + rr;
            float* cr = Cp + (size_t)row * N + n0;
#pragma unroll
            for (int j = 0; j < FN; ++j)
                cr[j * 16 + l16] = acc[i][j][rr];
        }
}

// ---------------- reduce over Z + bias + relu + bf16 cast (grid-stride) -----
static __device__ void reduce_stage(int gtid, int nt,
        const float* __restrict__ part, int zc, int mn4,
        const float* __restrict__ bias, int nmask,
        unsigned short* __restrict__ obf) {
    for (int idx = gtid; idx < mn4; idx += nt) {
        int idx4 = idx * 4;
        float4 acc = *(const float4*)(bias + (idx4 & nmask));
        const float4* p = (const float4*)part + idx;
        for (int z = 0; z < zc; ++z) {
            float4 v = p[(size_t)z * mn4];
            acc.x += v.x; acc.y += v.y; acc.z += v.z; acc.w += v.w;
        }
        acc.x = fmaxf(acc.x, 0.f); acc.y = fmaxf(acc.y, 0.f);
        acc.z = fmaxf(acc.z, 0.f); acc.w = fmaxf(acc.w, 0.f);
        ushort4 h;
        h.x = f2bf(acc.x); h.y = f2bf(acc.y); h.z = f2bf(acc.z); h.w = f2bf(acc.w);
        *(ushort4*)(obf + idx4) = h;
    }
}

// ---- G2-reduce + G3 fused, wave-parallel (block = roi) ---------------------
static __device__ void fc_stage(char* smem, int tid, int n,
        const float* __restrict__ part, int zc,
        const float* __restrict__ b2, const float* __restrict__ w3,
        const float* __restrict__ b3, float* __restrict__ out) {
    float* s = (float*)smem;   // 1024 floats
    float4 a4 = *(const float4*)(b2 + tid * 4);
    const float* pb = part + (size_t)n * 1024 + tid * 4;
    for (int z = 0; z < zc; ++z) {
        float4 v = *(const float4*)(pb + (size_t)z * (NROI * DFC));
        a4.x += v.x; a4.y += v.y; a4.z += v.z; a4.w += v.w;
    }
    a4.x = fmaxf(a4.x, 0.f); a4.y = fmaxf(a4.y, 0.f);
    a4.z = fmaxf(a4.z, 0.f); a4.w = fmaxf(a4.w, 0.f);
    *(float4*)(s + tid * 4) = a4;
    __syncthreads();
    int wv = tid >> 6, lane = tid & 63;
    for (int o = wv; o < 98; o += 4) {
        const float* w = w3 + (size_t)o * 1024 + lane;
        float a = 0.f;
#pragma unroll
        for (int i = 0; i < 16; ++i)
            a += w[i * 64] * s[lane + i * 64];
#pragma unroll
        for (int off = 32; off > 0; off >>= 1) a += __shfl_down(a, off);
        if (lane == 0) out[n * 98 + o] = b3[o] + a;
    }
}

// ---- G5-reduce + head fused (wave = roi) -----------------------------------
static __device__ void head_stage(int n, int lane,
        const float* __restrict__ part, int zc,
        const float* __restrict__ b4, const float* __restrict__ bw,
        const float* __restrict__ bb, float* __restrict__ out) {
    float a0 = 0, a1 = 0, a2 = 0, a3 = 0;
    for (int k = lane; k < 512; k += 64) {
        float acc = b4[k];
        for (int z = 0; z < zc; ++z)
            acc += part[(size_t)z * (NROI * FCC) + n * 512 + k];
        float v = fmaxf(acc, 0.f);
        a0 += v * bw[k]; a1 += v * bw[512 + k];
        a2 += v * bw[1024 + k]; a3 += v * bw[1536 + k];
    }
#pragma unroll
    for (int o = 32; o > 0; o >>= 1) {
        a0 += __shfl_down(a0, o); a1 += __shfl_down(a1, o);
        a2 += __shfl_down(a2, o); a3 += __shfl_down(a3, o);
    }
    if (lane == 0) {
        out[n * 4 + 0] = a0 + bb[0]; out[n * 4 + 1] = a1 + bb[1];
        out[n * 4 + 2] = a2 + bb[2]; out[n * 4 + 3] = a3 + bb[3];
    }
}

// ---------------------------------------------------------------------------
struct MegaArgs {
    const float *x, *rois;
    const float *off_w1, *off_b1, *off_w2, *off_b2, *off_w3, *off_b3;
    const float *fc1_w, *fc1_b, *fc2_w, *fc2_b, *box_w, *box_b;
    float* out;
    float* xT;
    unsigned short* P;
    unsigned short* h1b;
    float* offb;
    unsigned short* h3b;
    float* part;
    unsigned* bar;
    int zg1;
};

__global__ __launch_bounds__(256, 2) void mega(MegaArgs p) {
    __shared__ __align__(16) char smem[49152];
    const int bid = blockIdx.x, tid = threadIdx.x;
    const int gtid = bid * NTHR + tid;
    const int zg1 = p.zg1, zg4 = zg1 * 2;
    unsigned* bar = p.bar;

    // 1. transpose (1280 virtual blocks)
    for (int f = bid; f < 1280; f += NBLK) {
        transpose_it(smem, tid, f, p.x, p.xT);
        __syncthreads();
    }
    gbar(bar, bid, tid);
    // 2. pool pass 0 (512 blocks exactly)
    pool_stage(smem, tid, bid & 1, bid >> 1, p.xT, p.rois, nullptr, 0, p.P);
    gbar(bar, bid, tid);
    // 3. G1 partials (16 x zg1 blocks)
    if (bid < 16 * zg1)
        gemm_stage(smem, tid, p.P, p.off_w1, p.part, DFC, INF, 392 / zg1, bid & 15, bid >> 4);
    gbar(bar, bid, tid);
    // 4. red1 -> h1b
    reduce_stage(gtid, NBLK * NTHR, p.part, zg1, NROI * DFC / 4, p.off_b1, DFC - 1, p.h1b);
    gbar(bar, bid, tid);
    // 5. G2 partials (16 x 8 blocks)
    if (bid < 128)
        gemm_stage(smem, tid, p.h1b, p.off_w2, p.part, DFC, DFC, 4, bid & 15, bid >> 4);
    gbar(bar, bid, tid);
    // 6. fused G2-reduce + G3 (256 blocks)
    if (bid < NROI)
        fc_stage(smem, tid, bid, p.part, 8, p.off_b2, p.off_w3, p.off_b3, p.offb);
    gbar(bar, bid, tid);
    // 7. pool pass 1
    pool_stage(smem, tid, bid & 1, bid >> 1, p.xT, p.rois, p.offb, 1, p.P);
    gbar(bar, bid, tid);
    // 8. G4 partials (8 x zg4 blocks)
    if (bid < 8 * zg4)
        gemm_stage(smem, tid, p.P, p.fc1_w, p.part, FCC, INF, 392 / zg4, bid & 7, bid >> 3);
    gbar(bar, bid, tid);
    // 9. red4 -> h3b
    reduce_stage(gtid, NBLK * NTHR, p.part, zg4, NROI * FCC / 4, p.fc1_b, FCC - 1, p.h3b);
    gbar(bar, bid, tid);
    // 10. G5 partials (8 x 8 blocks)
    if (bid < 64)
        gemm_stage(smem, tid, p.h3b, p.fc2_w, p.part, FCC, FCC, 2, bid & 7, bid >> 3);
    gbar(bar, bid, tid);
    // 11. fused G5-reduce + head (64 blocks x 4 waves)
    if (bid < 64)
        head_stage(bid * 4 + (tid >> 6), tid & 63, p.part, 8, p.fc2_b, p.box_w, p.box_b, p.out);
}

// ---------------------------------------------------------------------------
extern "C" void kernel_launch(void* const* d_in, const int* in_sizes, int n_in,
                              void* d_out, int out_size, void* d_ws, size_t ws_size,
                              hipStream_t stream) {
    char* ws = (char*)d_ws;
    size_t o = 0;
    auto carve = [&](size_t bytes) { char* p = ws + o; o += (bytes + 255) & ~(size_t)255; return p; };
    float*          xT   = (float*)carve((size_t)NB * 625 * 256 * 4);   // 5.12 MB
    unsigned short* P    = (unsigned short*)carve((size_t)NROI * INF * 2);
    unsigned short* h1b  = (unsigned short*)carve((size_t)NROI * DFC * 2);
    float*          offb = (float*)carve((size_t)NROI * 98 * 4);
    unsigned short* h3b  = (unsigned short*)carve((size_t)NROI * FCC * 2);
    unsigned*       bar  = (unsigned*)carve(256);
    size_t fixed = o;
    const size_t SLAB = (size_t)NROI * DFC * 4;   // 1 MB
    int zg1;                        // tier on ws_size (constant -> graph-safe)
    if      (ws_size >= fixed + 28 * SLAB) zg1 = 28;
    else if (ws_size >= fixed + 14 * SLAB) zg1 = 14;
    else                                   zg1 = 7;
    float* part = (float*)carve((size_t)zg1 * SLAB);

    // reset barrier state every launch (graph-capture-safe async memset)
    hipMemsetAsync(bar, 0, 256, stream);

    MegaArgs ma;
    ma.x      = (const float*)d_in[0];
    ma.rois   = (const float*)d_in[1];
    ma.off_w1 = (const float*)d_in[2];
    ma.off_b1 = (const float*)d_in[3];
    ma.off_w2 = (const float*)d_in[4];
    ma.off_b2 = (const float*)d_in[5];
    ma.off_w3 = (const float*)d_in[6];
    ma.off_b3 = (const float*)d_in[7];
    ma.fc1_w  = (const float*)d_in[8];
    ma.fc1_b  = (const float*)d_in[9];
    ma.fc2_w  = (const float*)d_in[10];
    ma.fc2_b  = (const float*)d_in[11];
    ma.box_w  = (const float*)d_in[12];
    ma.box_b  = (const float*)d_in[13];
    ma.out    = (float*)d_out;
    ma.xT = xT; ma.P = P; ma.h1b = h1b; ma.offb = offb; ma.h3b = h3b;
    ma.part = part; ma.bar = bar; ma.zg1 = zg1;

    mega<<<dim3(NBLK), dim3(NTHR), 0, stream>>>(ma);
}

// Round 11
// 436.975 us; speedup vs baseline: 3.2706x; 3.2706x over previous
//
#include <hip/hip_runtime.h>
#include <hip/hip_bf16.h>

// ---------------------------------------------------------------------------
// FCx2DetHead pipeline. R16 = R15 with compile fix: __builtin_amdgcn_s_sleep
// needs a CONSTANT operand -> spin_ne templated on SLP. (R15's runtime `slp`
// param never compiled; R8/R9 infra failures masked it.)
// Experiment unchanged: mega-kernel, barrier memory-ordering fix.
// R14 passed (absmax 3.8e-6) but ran 1388us with HBM at 177 GB/s: per-poll
// ACQUIRE at agent scope = L2 invalidate per poll -> 64 spinners/XCD
// thrashed L2; plus 2x __threadfence per barrier. R16 keeps stage code +
// topology identical, changes ONLY the ordering:
//  - RELAXED spin polls, s_sleep backoff, acquire-load ONCE at exit.
//  - arrival publish = RELEASE fetch_add (one L2 wb), no __threadfence.
//  - two-level notify: gen (8 leader pollers) -> per-group ggen lines
//    (63 pollers each, 128B padded) -> caps same-line IC contention.
//  - escalation: every 64th poll is acquire (safety if relaxed were stale).
// ---------------------------------------------------------------------------

#define NROI 256
#define NB   8
#define INF  12544   // 256*49
#define DFC  1024
#define FCC  512
#define NBLK 512
#define NTHR 256
#define NGRP 8
#define GRPSZ (NBLK / NGRP)

typedef __attribute__((ext_vector_type(8))) short short8;
typedef __attribute__((ext_vector_type(4))) float floatx4;

static __device__ __forceinline__ unsigned short f2bf(float f) {
    unsigned int u = __float_as_uint(f);
    unsigned int r = (u + 0x7fffu + ((u >> 16) & 1u)) >> 16;
    return (unsigned short)r;
}

static __device__ __forceinline__ void async_copy16(const void* g, void* l) {
    __builtin_amdgcn_global_load_lds(
        (const __attribute__((address_space(1))) unsigned int*)g,
        (__attribute__((address_space(3))) unsigned int*)l, 16, 0, 0);
}

// ---------------- grid barrier ----------------------------------------------
// layout (128B-padded lines): gcnt[g]=bar+g*32, ggen[g]=bar+(8+g)*32,
// root=bar+16*32, gen=bar+17*32.
template <int SLP>
static __device__ __forceinline__ void spin_ne(unsigned* p, unsigned g) {
    for (int it = 0; it < 1000000; ++it) {
        unsigned v = __hip_atomic_load(p, __ATOMIC_RELAXED, __HIP_MEMORY_SCOPE_AGENT);
        if (v != g) return;
        if ((it & 63) == 63) {   // safety escalation: paced acquire
            v = __hip_atomic_load(p, __ATOMIC_ACQUIRE, __HIP_MEMORY_SCOPE_AGENT);
            if (v != g) return;
        }
        __builtin_amdgcn_s_sleep(SLP);
    }
}

static __device__ __forceinline__ void gbar(unsigned* bar, int bid, int tid) {
    __syncthreads();
    if (tid == 0) {
        const int grp = bid >> 6;
        unsigned* gcnt = bar + grp * 32;
        unsigned* ggen = bar + (8 + grp) * 32;
        unsigned* root = bar + 16 * 32;
        unsigned* gen  = bar + 17 * 32;
        unsigned gg = __hip_atomic_load(ggen, __ATOMIC_RELAXED, __HIP_MEMORY_SCOPE_AGENT);
        // arrival: RELEASE publishes this block's prior writes (one L2 wb)
        unsigned a = __hip_atomic_fetch_add(gcnt, 1u, __ATOMIC_RELEASE, __HIP_MEMORY_SCOPE_AGENT);
        if (a == GRPSZ - 1) {                    // group leader (last arriver)
            unsigned gv = __hip_atomic_load(gen, __ATOMIC_RELAXED, __HIP_MEMORY_SCOPE_AGENT);
            unsigned r = __hip_atomic_fetch_add(root, 1u, __ATOMIC_ACQ_REL, __HIP_MEMORY_SCOPE_AGENT);
            if (r == NGRP - 1) {
                __hip_atomic_store(root, 0u, __ATOMIC_RELAXED, __HIP_MEMORY_SCOPE_AGENT);
                __hip_atomic_store(gen, gv + 1u, __ATOMIC_RELEASE, __HIP_MEMORY_SCOPE_AGENT);
            } else {
                spin_ne<4>(gen, gv);             // 8 pollers, fast notify
            }
            __hip_atomic_store(gcnt, 0u, __ATOMIC_RELAXED, __HIP_MEMORY_SCOPE_AGENT);
            __hip_atomic_store(ggen, gg + 1u, __ATOMIC_RELEASE, __HIP_MEMORY_SCOPE_AGENT);
        } else {
            spin_ne<15>(ggen, gg);               // 63 pollers, padded line
        }
        // single acquire: invalidate stale L1/L2 before reading others' data
        (void)__hip_atomic_load(gen, __ATOMIC_ACQUIRE, __HIP_MEMORY_SCOPE_AGENT);
    }
    __syncthreads();
}

// ---------------- transpose x (B,C,H,W) -> feat (B,H,W,C), one virt block ---
static __device__ __forceinline__ void transpose_it(char* smem, int tid, int f,
        const float* __restrict__ x, float* __restrict__ xT) {
    float (*t)[33] = (float(*)[33])smem;
    int xb = f % 20, yb = (f / 20) & 7, b = f / 160;
    int cb = yb * 32, lb = xb * 32;
    int tx = tid & 31, ty = tid >> 5;
#pragma unroll
    for (int r = 0; r < 4; ++r) {
        int c = cb + ty + r * 8, l = lb + tx;
        if (l < 625) t[ty + r * 8][tx] = x[(size_t)(b * 256 + c) * 625 + l];
    }
    __syncthreads();
#pragma unroll
    for (int r = 0; r < 4; ++r) {
        int l = lb + ty + r * 8, c = cb + tx;
        if (l < 625) xT[((size_t)b * 625 + l) * 256 + c] = t[tx][ty + r * 8];
    }
}

// ---------------- fused deformable RoI pool (prep + gather) -----------------
static __device__ void pool_stage(char* smem, int tid, int q, int n,
        const float* __restrict__ feat, const float* __restrict__ rois,
        const float* __restrict__ off, int has_off,
        unsigned short* __restrict__ P) {
    float (*sGrid)[16] = (float(*)[16])smem;                 // 3136 B
    int* sBase = (int*)(smem + 3136);                        // 196 B
    unsigned short* sOut = (unsigned short*)(smem + 3584);   // 12544 B
    const float SSC = (float)(25.0 / 255.0);

    if (tid < 49) {
        int bin = tid;
        const float* r = rois + n * 5;
        int b = (int)r[0];
        float sw = rintf(r[1]) * SSC - 0.5f;
        float sh = rintf(r[2]) * SSC - 0.5f;
        float rw = fmaxf((rintf(r[3]) + 1.0f) * SSC - 0.5f - sw, 0.1f);
        float rh = fmaxf((rintf(r[4]) + 1.0f) * SSC - 0.5f - sh, 0.1f);
        float bw = rw / 7.0f, bh = rh / 7.0f;
        float bws = bw * 0.25f, bhs = bh * 0.25f;
        int ph = bin / 7, pw = bin - ph * 7;
        float tx = 0.f, ty = 0.f;
        if (has_off) {
            tx = off[n * 98 + bin] * 0.1f;
            ty = off[n * 98 + 49 + bin] * 0.1f;
        }
        float wstart = pw * bw + sw + tx * rw;
        float hstart = ph * bh + sh + ty * rh;
#pragma unroll
        for (int i = 0; i < 16; ++i) sGrid[bin][i] = 0.f;
        int gy0 = 0, gx0 = 0, cnt = 0;
#pragma unroll
        for (int s = 0; s < 16; ++s) {
            float fx = wstart + (s & 3) * bws;
            float fy = hstart + (s >> 2) * bhs;
            bool valid = (fx >= -0.5f) && (fx <= 24.5f) && (fy >= -0.5f) && (fy <= 24.5f);
            float xc = fminf(fmaxf(fx, 0.f), 24.f);
            float yc = fminf(fmaxf(fy, 0.f), 24.f);
            float x0f = floorf(xc), y0f = floorf(yc);
            float dx = xc - x0f, dy = yc - y0f;
            int x0 = (int)x0f, y0 = (int)y0f;
            int x1 = (int)ceilf(xc), y1 = (int)ceilf(yc);
            if (s == 0) { gy0 = y0; gx0 = x0; }
            float w00 = (1.f - dx) * (1.f - dy), w01 = dx * (1.f - dy);
            float w10 = (1.f - dx) * dy,         w11 = dx * dy;
            if (!valid) { w00 = w01 = w10 = w11 = 0.f; }
            cnt += valid ? 1 : 0;
            int ry0 = (y0 - gy0) * 4, ry1 = (y1 - gy0) * 4;
            sGrid[bin][ry0 + (x0 - gx0)] += w00;
            sGrid[bin][ry0 + (x1 - gx0)] += w01;
            sGrid[bin][ry1 + (x0 - gx0)] += w10;
            sGrid[bin][ry1 + (x1 - gx0)] += w11;
        }
        float inv = 1.0f / fmaxf((float)cnt, 1.0f);
#pragma unroll
        for (int i = 0; i < 16; ++i) sGrid[bin][i] *= inv;
        sBase[bin] = gy0 | (gx0 << 8) | (b << 16);
    }
    __syncthreads();

    int wv = tid >> 6, lane = tid & 63;
    int cbase = q * 128 + lane * 2;
    for (int bin = wv; bin < 49; bin += 4) {
        int base = sBase[bin];
        int gy0 = base & 255, gx0 = (base >> 8) & 255, b = base >> 16;
        const float4* wp = (const float4*)sGrid[bin];
        float4 w0 = wp[0], w1 = wp[1], w2 = wp[2], w3 = wp[3];
        float ww[16] = { w0.x, w0.y, w0.z, w0.w, w1.x, w1.y, w1.z, w1.w,
                         w2.x, w2.y, w2.z, w2.w, w3.x, w3.y, w3.z, w3.w };
        int rowOff[4], colOff[4];
#pragma unroll
        for (int r = 0; r < 4; ++r) {
            rowOff[r] = min(gy0 + r, 24) * 25;
            colOff[r] = min(gx0 + r, 24);
        }
        int b625 = b * 625;
        float ax = 0.f, ay = 0.f;
#pragma unroll
        for (int cell = 0; cell < 16; ++cell) {
            int pix = b625 + rowOff[cell >> 2] + colOff[cell & 3];
            float2 v = *(const float2*)(feat + (size_t)pix * 256 + cbase);
            ax += ww[cell] * v.x;
            ay += ww[cell] * v.y;
        }
        sOut[(lane * 2) * 49 + bin] = f2bf(ax);
        sOut[(lane * 2 + 1) * 49 + bin] = f2bf(ay);
    }
    __syncthreads();
    const uint2* so = (const uint2*)sOut;
    uint2* dp = (uint2*)(P + (size_t)n * INF + q * 128 * 49);
    for (int i = tid; i < 128 * 49 / 4; i += 256) dp[i] = so[i];
}

// ---------------- 2-phase MFMA GEMM (BM=256=M, BN=64) -> fp32 partials ------
static __device__ void gemm_stage(char* smem, int tid,
        const unsigned short* __restrict__ A, const float* __restrict__ Bw,
        float* __restrict__ Cpart, int N, int K, int kSteps, int nb, int z) {
    constexpr int BM = 256, BN = 64;
    constexpr int FM = 4, FN = 4;
    unsigned short* AsB = (unsigned short*)smem;      // 2 slots x 8192 shorts
    float* BsB = (float*)(smem + 32768);              // 2 slots x 2048 floats
    const int lane = tid & 63;
    const int wave = tid >> 6;
    const int n0 = nb * BN;
    const int k0 = z * kSteps * 32;
    const int quad = lane >> 4;
    const int l16 = lane & 15;

    floatx4 acc[FM][FN];
#pragma unroll
    for (int i = 0; i < FM; ++i)
#pragma unroll
        for (int j = 0; j < FN; ++j) acc[i][j] = (floatx4)0.f;

    const unsigned short* ag[4];
    int albase[4];
#pragma unroll
    for (int i = 0; i < 4; ++i) {
        int idx = tid + i * 256;
        int row = idx >> 2;
        int kg4 = (idx & 3) ^ ((row >> 1) & 3);
        ag[i] = A + (size_t)row * K + kg4 * 8;
        albase[i] = (i * 256 + wave * 64) * 16;   // wave-uniform byte base
    }
    const float* bg[2];
    int blbase[2];
#pragma unroll
    for (int i = 0; i < 2; ++i) {
        int idx = tid + i * 256;
        int row = idx >> 3;
        int kg = (idx & 7) ^ ((row >> 1) & 7);
        bg[i] = Bw + (size_t)(n0 + row) * K + kg * 4;
        blbase[i] = (i * 256 + wave * 64) * 16;
    }

    auto issue = [&](int slot, int kk) {
#pragma unroll
        for (int i = 0; i < 4; ++i)
            async_copy16(ag[i] + kk, smem + slot * 16384 + albase[i]);
#pragma unroll
        for (int i = 0; i < 2; ++i)
            async_copy16(bg[i] + kk, smem + 32768 + slot * 8192 + blbase[i]);
    };

    issue(0, k0);
    __syncthreads();

    int cur = 0;
    for (int ks = 0; ks < kSteps; ++ks) {
        if (ks + 1 < kSteps) issue(cur ^ 1, k0 + (ks + 1) * 32);
        short8 a[FM], bf[FN];
        const unsigned short* Asc = AsB + cur * 8192;
        const float* Bsc = BsB + cur * 2048;
#pragma unroll
        for (int i = 0; i < FM; ++i) {
            int r = wave * 64 + i * 16 + l16;
            int sl = quad ^ ((r >> 1) & 3);
            a[i] = *(const short8*)(Asc + r * 32 + sl * 8);
        }
#pragma unroll
        for (int j = 0; j < FN; ++j) {
            int r = j * 16 + l16;
            int sw8 = (r >> 1) & 7;
            int g0 = (quad * 2) ^ sw8;
            int g1 = (quad * 2 + 1) ^ sw8;
            float4 v0 = *(const float4*)(Bsc + r * 32 + g0 * 4);
            float4 v1 = *(const float4*)(Bsc + r * 32 + g1 * 4);
            bf[j][0] = (short)f2bf(v0.x); bf[j][1] = (short)f2bf(v0.y);
            bf[j][2] = (short)f2bf(v0.z); bf[j][3] = (short)f2bf(v0.w);
            bf[j][4] = (short)f2bf(v1.x); bf[j][5] = (short)f2bf(v1.y);
            bf[j][6] = (short)f2bf(v1.z); bf[j][7] = (short)f2bf(v1.w);
        }
#pragma unroll
        for (int i = 0; i < FM; ++i)
#pragma unroll
            for (int j = 0; j < FN; ++j)
                acc[i][j] = __builtin_amdgcn_mfma_f32_16x16x32_bf16(a[i], bf[j], acc[i][j], 0, 0, 0);
        __syncthreads();
        cur ^= 1;
    }
    float* Cp = Cpart + (size_t)z * BM * N;
#pragma unroll
    for (int i = 0; i < FM; ++i)
#pragma unroll
        for (int rr = 0; rr < 4; ++rr) {
            int row = wave * 64 + i * 16 + quad * 4 + rr;
            float* cr = Cp + (size_t)row * N + n0;
#pragma unroll
            for (int j = 0; j < FN; ++j)
                cr[j * 16 + l16] = acc[i][j][rr];
        }
}

// ---------------- reduce over Z + bias + relu + bf16 cast (grid-stride) -----
static __device__ void reduce_stage(int gtid, int nt,
        const float* __restrict__ part, int zc, int mn4,
        const float* __restrict__ bias, int nmask,
        unsigned short* __restrict__ obf) {
    for (int idx = gtid; idx < mn4; idx += nt) {
        int idx4 = idx * 4;
        float4 acc = *(const float4*)(bias + (idx4 & nmask));
        const float4* p = (const float4*)part + idx;
        for (int z = 0; z < zc; ++z) {
            float4 v = p[(size_t)z * mn4];
            acc.x += v.x; acc.y += v.y; acc.z += v.z; acc.w += v.w;
        }
        acc.x = fmaxf(acc.x, 0.f); acc.y = fmaxf(acc.y, 0.f);
        acc.z = fmaxf(acc.z, 0.f); acc.w = fmaxf(acc.w, 0.f);
        ushort4 h;
        h.x = f2bf(acc.x); h.y = f2bf(acc.y); h.z = f2bf(acc.z); h.w = f2bf(acc.w);
        *(ushort4*)(obf + idx4) = h;
    }
}

// ---- G2-reduce + G3 fused, wave-parallel (block = roi) ---------------------
static __device__ void fc_stage(char* smem, int tid, int n,
        const float* __restrict__ part, int zc,
        const float* __restrict__ b2, const float* __restrict__ w3,
        const float* __restrict__ b3, float* __restrict__ out) {
    float* s = (float*)smem;   // 1024 floats
    float4 a4 = *(const float4*)(b2 + tid * 4);
    const float* pb = part + (size_t)n * 1024 + tid * 4;
    for (int z = 0; z < zc; ++z) {
        float4 v = *(const float4*)(pb + (size_t)z * (NROI * DFC));
        a4.x += v.x; a4.y += v.y; a4.z += v.z; a4.w += v.w;
    }
    a4.x = fmaxf(a4.x, 0.f); a4.y = fmaxf(a4.y, 0.f);
    a4.z = fmaxf(a4.z, 0.f); a4.w = fmaxf(a4.w, 0.f);
    *(float4*)(s + tid * 4) = a4;
    __syncthreads();
    int wv = tid >> 6, lane = tid & 63;
    for (int o = wv; o < 98; o += 4) {
        const float* w = w3 + (size_t)o * 1024 + lane;
        float a = 0.f;
#pragma unroll
        for (int i = 0; i < 16; ++i)
            a += w[i * 64] * s[lane + i * 64];
#pragma unroll
        for (int off = 32; off > 0; off >>= 1) a += __shfl_down(a, off);
        if (lane == 0) out[n * 98 + o] = b3[o] + a;
    }
}

// ---- G5-reduce + head fused (wave = roi) -----------------------------------
static __device__ void head_stage(int n, int lane,
        const float* __restrict__ part, int zc,
        const float* __restrict__ b4, const float* __restrict__ bw,
        const float* __restrict__ bb, float* __restrict__ out) {
    float a0 = 0, a1 = 0, a2 = 0, a3 = 0;
    for (int k = lane; k < 512; k += 64) {
        float acc = b4[k];
        for (int z = 0; z < zc; ++z)
            acc += part[(size_t)z * (NROI * FCC) + n * 512 + k];
        float v = fmaxf(acc, 0.f);
        a0 += v * bw[k]; a1 += v * bw[512 + k];
        a2 += v * bw[1024 + k]; a3 += v * bw[1536 + k];
    }
#pragma unroll
    for (int o = 32; o > 0; o >>= 1) {
        a0 += __shfl_down(a0, o); a1 += __shfl_down(a1, o);
        a2 += __shfl_down(a2, o); a3 += __shfl_down(a3, o);
    }
    if (lane == 0) {
        out[n * 4 + 0] = a0 + bb[0]; out[n * 4 + 1] = a1 + bb[1];
        out[n * 4 + 2] = a2 + bb[2]; out[n * 4 + 3] = a3 + bb[3];
    }
}

// ---------------------------------------------------------------------------
struct MegaArgs {
    const float *x, *rois;
    const float *off_w1, *off_b1, *off_w2, *off_b2, *off_w3, *off_b3;
    const float *fc1_w, *fc1_b, *fc2_w, *fc2_b, *box_w, *box_b;
    float* out;
    float* xT;
    unsigned short* P;
    unsigned short* h1b;
    float* offb;
    unsigned short* h3b;
    float* part;
    unsigned* bar;
    int zg1;
};

__global__ __launch_bounds__(256, 2) void mega(MegaArgs p) {
    __shared__ __align__(16) char smem[49152];
    const int bid = blockIdx.x, tid = threadIdx.x;
    const int gtid = bid * NTHR + tid;
    const int zg1 = p.zg1, zg4 = zg1 * 2;
    unsigned* bar = p.bar;

    // 1. transpose (1280 virtual blocks)
    for (int f = bid; f < 1280; f += NBLK) {
        transpose_it(smem, tid, f, p.x, p.xT);
        __syncthreads();
    }
    gbar(bar, bid, tid);
    // 2. pool pass 0 (512 blocks exactly)
    pool_stage(smem, tid, bid & 1, bid >> 1, p.xT, p.rois, nullptr, 0, p.P);
    gbar(bar, bid, tid);
    // 3. G1 partials (16 x zg1 blocks)
    if (bid < 16 * zg1)
        gemm_stage(smem, tid, p.P, p.off_w1, p.part, DFC, INF, 392 / zg1, bid & 15, bid >> 4);
    gbar(bar, bid, tid);
    // 4. red1 -> h1b
    reduce_stage(gtid, NBLK * NTHR, p.part, zg1, NROI * DFC / 4, p.off_b1, DFC - 1, p.h1b);
    gbar(bar, bid, tid);
    // 5. G2 partials (16 x 8 blocks)
    if (bid < 128)
        gemm_stage(smem, tid, p.h1b, p.off_w2, p.part, DFC, DFC, 4, bid & 15, bid >> 4);
    gbar(bar, bid, tid);
    // 6. fused G2-reduce + G3 (256 blocks)
    if (bid < NROI)
        fc_stage(smem, tid, bid, p.part, 8, p.off_b2, p.off_w3, p.off_b3, p.offb);
    gbar(bar, bid, tid);
    // 7. pool pass 1
    pool_stage(smem, tid, bid & 1, bid >> 1, p.xT, p.rois, p.offb, 1, p.P);
    gbar(bar, bid, tid);
    // 8. G4 partials (8 x zg4 blocks)
    if (bid < 8 * zg4)
        gemm_stage(smem, tid, p.P, p.fc1_w, p.part, FCC, INF, 392 / zg4, bid & 7, bid >> 3);
    gbar(bar, bid, tid);
    // 9. red4 -> h3b
    reduce_stage(gtid, NBLK * NTHR, p.part, zg4, NROI * FCC / 4, p.fc1_b, FCC - 1, p.h3b);
    gbar(bar, bid, tid);
    // 10. G5 partials (8 x 8 blocks)
    if (bid < 64)
        gemm_stage(smem, tid, p.h3b, p.fc2_w, p.part, FCC, FCC, 2, bid & 7, bid >> 3);
    gbar(bar, bid, tid);
    // 11. fused G5-reduce + head (64 blocks x 4 waves)
    if (bid < 64)
        head_stage(bid * 4 + (tid >> 6), tid & 63, p.part, 8, p.fc2_b, p.box_w, p.box_b, p.out);
}

// ---------------------------------------------------------------------------
extern "C" void kernel_launch(void* const* d_in, const int* in_sizes, int n_in,
                              void* d_out, int out_size, void* d_ws, size_t ws_size,
                              hipStream_t stream) {
    char* ws = (char*)d_ws;
    size_t o = 0;
    auto carve = [&](size_t bytes) { char* p = ws + o; o += (bytes + 255) & ~(size_t)255; return p; };
    float*          xT   = (float*)carve((size_t)NB * 625 * 256 * 4);   // 5.12 MB
    unsigned short* P    = (unsigned short*)carve((size_t)NROI * INF * 2);
    unsigned short* h1b  = (unsigned short*)carve((size_t)NROI * DFC * 2);
    float*          offb = (float*)carve((size_t)NROI * 98 * 4);
    unsigned short* h3b  = (unsigned short*)carve((size_t)NROI * FCC * 2);
    unsigned*       bar  = (unsigned*)carve(4096);
    size_t fixed = o;
    const size_t SLAB = (size_t)NROI * DFC * 4;   // 1 MB
    int zg1;                        // tier on ws_size (constant -> graph-safe)
    if      (ws_size >= fixed + 28 * SLAB) zg1 = 28;
    else if (ws_size >= fixed + 14 * SLAB) zg1 = 14;
    else                                   zg1 = 7;
    float* part = (float*)carve((size_t)zg1 * SLAB);

    // reset barrier state every launch (graph-capture-safe async memset)
    (void)hipMemsetAsync(bar, 0, 4096, stream);

    MegaArgs ma;
    ma.x      = (const float*)d_in[0];
    ma.rois   = (const float*)d_in[1];
    ma.off_w1 = (const float*)d_in[2];
    ma.off_b1 = (const float*)d_in[3];
    ma.off_w2 = (const float*)d_in[4];
    ma.off_b2 = (const float*)d_in[5];
    ma.off_w3 = (const float*)d_in[6];
    ma.off_b3 = (const float*)d_in[7];
    ma.fc1_w  = (const float*)d_in[8];
    ma.fc1_b  = (const float*)d_in[9];
    ma.fc2_w  = (const float*)d_in[10];
    ma.fc2_b  = (const float*)d_in[11];
    ma.box_w  = (const float*)d_in[12];
    ma.box_b  = (const float*)d_in[13];
    ma.out    = (float*)d_out;
    ma.xT = xT; ma.P = P; ma.h1b = h1b; ma.offb = offb; ma.h3b = h3b;
    ma.part = part; ma.bar = bar; ma.zg1 = zg1;

    mega<<<dim3(NBLK), dim3(NTHR), 0, stream>>>(ma);
}

// Round 12
// 292.068 us; speedup vs baseline: 4.8932x; 1.4961x over previous
//
#include <hip/hip_runtime.h>
#include <hip/hip_bf16.h>

// ---------------------------------------------------------------------------
// FCx2DetHead pipeline. R17: restore R12 exactly (verified 288.79us).
// Mega-kernel arc (R13-R16) post-mortem: hand-rolled barrier fixed the L2
// invalidate storm (1388->333us) but mega's internal inflation (pinned-block
// imbalance + per-barrier L2 wipe + 11 barriers ~ 143us) exceeds the launch
// gap savings (~60us) -> multi-launch R12 structure is measured-better.
//  - gemm: R10 2-phase loop (stage-next -> MFMA-cur -> __syncthreads),
//    BN=64, 48KB LDS, all staging via global_load_lds, f2bf at consume.
//  - fc_small_red wave-parallel; reduce(G2)+G3 and reduce(G5)+head fused.
// ---------------------------------------------------------------------------

#define NROI 256
#define NB   8
#define INF  12544   // 256*49
#define DFC  1024
#define FCC  512

typedef __attribute__((ext_vector_type(8))) short short8;
typedef __attribute__((ext_vector_type(4))) float floatx4;

static __device__ __forceinline__ unsigned short f2bf(float f) {
    unsigned int u = __float_as_uint(f);
    unsigned int r = (u + 0x7fffu + ((u >> 16) & 1u)) >> 16;
    return (unsigned short)r;
}

static __device__ __forceinline__ void async_copy16(const void* g, void* l) {
    __builtin_amdgcn_global_load_lds(
        (const __attribute__((address_space(1))) unsigned int*)g,
        (__attribute__((address_space(3))) unsigned int*)l, 16, 0, 0);
}

// ---------------- transpose x (B,C,H,W) -> feat (B,H,W,C) -------------------
__global__ __launch_bounds__(256) void transpose_kernel(
        const float* __restrict__ x, float* __restrict__ xT) {
    __shared__ float t[32][33];
    int b  = blockIdx.z;
    int cb = blockIdx.y * 32;     // channel tile
    int lb = blockIdx.x * 32;     // hw tile (0..624)
    int tx = threadIdx.x & 31, ty = threadIdx.x >> 5;
#pragma unroll
    for (int r = 0; r < 4; ++r) {
        int c = cb + ty + r * 8, l = lb + tx;
        if (l < 625) t[ty + r * 8][tx] = x[(size_t)(b * 256 + c) * 625 + l];
    }
    __syncthreads();
#pragma unroll
    for (int r = 0; r < 4; ++r) {
        int l = lb + ty + r * 8, c = cb + tx;
        if (l < 625) xT[((size_t)b * 625 + l) * 256 + c] = t[tx][ty + r * 8];
    }
}

// ---------------- fused deformable RoI pool (prep + gather) -----------------
__global__ __launch_bounds__(256) void pool_kernel(
        const float* __restrict__ feat, const float* __restrict__ rois,
        const float* __restrict__ off, int has_off,
        unsigned short* __restrict__ P) {
    __shared__ float sGrid[49][16];
    __shared__ int   sBase[49];
    __shared__ unsigned short sOut[128 * 49];
    const float SSC = (float)(25.0 / 255.0);
    int q = blockIdx.x;            // channel half
    int n = blockIdx.y;            // roi
    int tid = threadIdx.x;

    if (tid < 49) {
        int bin = tid;
        const float* r = rois + n * 5;
        int b = (int)r[0];
        float sw = rintf(r[1]) * SSC - 0.5f;
        float sh = rintf(r[2]) * SSC - 0.5f;
        float rw = fmaxf((rintf(r[3]) + 1.0f) * SSC - 0.5f - sw, 0.1f);
        float rh = fmaxf((rintf(r[4]) + 1.0f) * SSC - 0.5f - sh, 0.1f);
        float bw = rw / 7.0f, bh = rh / 7.0f;
        float bws = bw * 0.25f, bhs = bh * 0.25f;
        int ph = bin / 7, pw = bin - ph * 7;
        float tx = 0.f, ty = 0.f;
        if (has_off) {
            tx = off[n * 98 + bin] * 0.1f;
            ty = off[n * 98 + 49 + bin] * 0.1f;
        }
        float wstart = pw * bw + sw + tx * rw;
        float hstart = ph * bh + sh + ty * rh;
#pragma unroll
        for (int i = 0; i < 16; ++i) sGrid[bin][i] = 0.f;
        int gy0 = 0, gx0 = 0, cnt = 0;
#pragma unroll
        for (int s = 0; s < 16; ++s) {
            float fx = wstart + (s & 3) * bws;
            float fy = hstart + (s >> 2) * bhs;
            bool valid = (fx >= -0.5f) && (fx <= 24.5f) && (fy >= -0.5f) && (fy <= 24.5f);
            float xc = fminf(fmaxf(fx, 0.f), 24.f);
            float yc = fminf(fmaxf(fy, 0.f), 24.f);
            float x0f = floorf(xc), y0f = floorf(yc);
            float dx = xc - x0f, dy = yc - y0f;
            int x0 = (int)x0f, y0 = (int)y0f;
            int x1 = (int)ceilf(xc), y1 = (int)ceilf(yc);
            if (s == 0) { gy0 = y0; gx0 = x0; }
            float w00 = (1.f - dx) * (1.f - dy), w01 = dx * (1.f - dy);
            float w10 = (1.f - dx) * dy,         w11 = dx * dy;
            if (!valid) { w00 = w01 = w10 = w11 = 0.f; }
            cnt += valid ? 1 : 0;
            int ry0 = (y0 - gy0) * 4, ry1 = (y1 - gy0) * 4;
            sGrid[bin][ry0 + (x0 - gx0)] += w00;
            sGrid[bin][ry0 + (x1 - gx0)] += w01;
            sGrid[bin][ry1 + (x0 - gx0)] += w10;
            sGrid[bin][ry1 + (x1 - gx0)] += w11;
        }
        float inv = 1.0f / fmaxf((float)cnt, 1.0f);
#pragma unroll
        for (int i = 0; i < 16; ++i) sGrid[bin][i] *= inv;
        sBase[bin] = gy0 | (gx0 << 8) | (b << 16);
    }
    __syncthreads();

    int wv = tid >> 6, lane = tid & 63;
    int cbase = q * 128 + lane * 2;
    for (int bin = wv; bin < 49; bin += 4) {
        int base = sBase[bin];
        int gy0 = base & 255, gx0 = (base >> 8) & 255, b = base >> 16;
        const float4* wp = (const float4*)sGrid[bin];
        float4 w0 = wp[0], w1 = wp[1], w2 = wp[2], w3 = wp[3];
        float ww[16] = { w0.x, w0.y, w0.z, w0.w, w1.x, w1.y, w1.z, w1.w,
                         w2.x, w2.y, w2.z, w2.w, w3.x, w3.y, w3.z, w3.w };
        int rowOff[4], colOff[4];
#pragma unroll
        for (int r = 0; r < 4; ++r) {
            rowOff[r] = min(gy0 + r, 24) * 25;
            colOff[r] = min(gx0 + r, 24);
        }
        int b625 = b * 625;
        float ax = 0.f, ay = 0.f;
#pragma unroll
        for (int cell = 0; cell < 16; ++cell) {
            int pix = b625 + rowOff[cell >> 2] + colOff[cell & 3];
            float2 v = *(const float2*)(feat + (size_t)pix * 256 + cbase);
            ax += ww[cell] * v.x;
            ay += ww[cell] * v.y;
        }
        sOut[(lane * 2) * 49 + bin] = f2bf(ax);
        sOut[(lane * 2 + 1) * 49 + bin] = f2bf(ay);
    }
    __syncthreads();
    const uint2* so = (const uint2*)sOut;
    uint2* dp = (uint2*)(P + (size_t)n * INF + q * 128 * 49);
    for (int i = tid; i < 128 * 49 / 4; i += 256) dp[i] = so[i];
}

// ---------------- 2-phase MFMA GEMM (BM=256=M, BN=64) -> fp32 partials ------
// R10-measured config: STAGE(next buf) -> ds_read+MFMA(cur buf) ->
// __syncthreads. D=2, 48 KB LDS -> 3 blocks/CU. 6 global_load_lds per thread
// per k-step (4x A 16B bf16, 2x B 16B fp32), f2bf at consume.
// A swizzle: 16B-unit kg4 ^= (row>>1)&3. B swizzle: kg ^= (row>>1)&7.
__global__ __launch_bounds__(256) void gemm_pipe(
        const unsigned short* __restrict__ A, const float* __restrict__ Bw,
        float* __restrict__ Cpart, int N, int K, int kSteps) {
    constexpr int BM = 256, BN = 64;
    constexpr int FM = 4, FN = 4;
    __shared__ unsigned short As[2][BM * 32];  // 16 KB / slot
    __shared__ float          Bs[2][BN * 32];  //  8 KB / slot
    const int tid = threadIdx.x;
    const int lane = tid & 63;
    const int wave = tid >> 6;
    const int n0 = blockIdx.x * BN;
    const int k0 = blockIdx.z * kSteps * 32;
    const int quad = lane >> 4;
    const int l16 = lane & 15;

    floatx4 acc[FM][FN];
#pragma unroll
    for (int i = 0; i < FM; ++i)
#pragma unroll
        for (int j = 0; j < FN; ++j) acc[i][j] = (floatx4)0.f;

    // A staging: thread t, copy i -> LDS 16B-unit (i*256 + t)
    const unsigned short* ag[4];
    int albase[4];
#pragma unroll
    for (int i = 0; i < 4; ++i) {
        int idx = tid + i * 256;
        int row = idx >> 2;
        int kg4 = (idx & 3) ^ ((row >> 1) & 3);
        ag[i] = A + (size_t)row * K + kg4 * 8;
        albase[i] = (i * 256 + wave * 64) * 16;   // wave-uniform byte base
    }
    // B staging: thread t, copy i -> LDS 16B-unit (i*256 + t); 512 units
    const float* bg[2];
    int blbase[2];
#pragma unroll
    for (int i = 0; i < 2; ++i) {
        int idx = tid + i * 256;
        int row = idx >> 3;
        int kg = (idx & 7) ^ ((row >> 1) & 7);
        bg[i] = Bw + (size_t)(n0 + row) * K + kg * 4;
        blbase[i] = (i * 256 + wave * 64) * 16;
    }

    auto issue = [&](int slot, int kk) {
#pragma unroll
        for (int i = 0; i < 4; ++i)
            async_copy16(ag[i] + kk, (char*)&As[slot][0] + albase[i]);
#pragma unroll
        for (int i = 0; i < 2; ++i)
            async_copy16(bg[i] + kk, (char*)&Bs[slot][0] + blbase[i]);
    };

    // prologue: stage k-step 0 into slot 0; __syncthreads drains vmcnt
    issue(0, k0);
    __syncthreads();

    int cur = 0;
    for (int ks = 0; ks < kSteps; ++ks) {
        // stage next k-step into the other slot (issued before compute;
        // the end-of-iter __syncthreads drains it before it is consumed)
        if (ks + 1 < kSteps) issue(cur ^ 1, k0 + (ks + 1) * 32);
        // fragments from slot cur
        short8 a[FM], bf[FN];
#pragma unroll
        for (int i = 0; i < FM; ++i) {
            int r = wave * 64 + i * 16 + l16;
            int sl = quad ^ ((r >> 1) & 3);
            a[i] = *(const short8*)(&As[cur][0] + r * 32 + sl * 8);
        }
#pragma unroll
        for (int j = 0; j < FN; ++j) {
            int r = j * 16 + l16;
            int sw8 = (r >> 1) & 7;
            int g0 = (quad * 2) ^ sw8;
            int g1 = (quad * 2 + 1) ^ sw8;
            float4 v0 = *(const float4*)(&Bs[cur][0] + r * 32 + g0 * 4);
            float4 v1 = *(const float4*)(&Bs[cur][0] + r * 32 + g1 * 4);
            bf[j][0] = (short)f2bf(v0.x); bf[j][1] = (short)f2bf(v0.y);
            bf[j][2] = (short)f2bf(v0.z); bf[j][3] = (short)f2bf(v0.w);
            bf[j][4] = (short)f2bf(v1.x); bf[j][5] = (short)f2bf(v1.y);
            bf[j][6] = (short)f2bf(v1.z); bf[j][7] = (short)f2bf(v1.w);
        }
#pragma unroll
        for (int i = 0; i < FM; ++i)
#pragma unroll
            for (int j = 0; j < FN; ++j)
                acc[i][j] = __builtin_amdgcn_mfma_f32_16x16x32_bf16(a[i], bf[j], acc[i][j], 0, 0, 0);
        __syncthreads();
        cur ^= 1;
    }
    // epilogue: full contiguous row spans (complete cache lines)
    float* Cp = Cpart + (size_t)blockIdx.z * BM * N;
#pragma unroll
    for (int i = 0; i < FM; ++i)
#pragma unroll
        for (int rr = 0; rr < 4; ++rr) {
            int row = wave * 64 + i * 16 + quad * 4 + rr;
            float* cr = Cp + (size_t)row * N + n0;
#pragma unroll
            for (int j = 0; j < FN; ++j)
                cr[j * 16 + l16] = acc[i][j][rr];
        }
}

// ---------------- reduce over Z + bias + relu + bf16 cast (G1/G4) -----------
__global__ __launch_bounds__(256) void reduce_bias(
        const float* __restrict__ part, int zc, int mn4,
        const float* __restrict__ bias, int nmask, int relu,
        unsigned short* __restrict__ obf, float* __restrict__ of) {
    int idx = blockIdx.x * 256 + threadIdx.x;    // float4 index
    if (idx >= mn4) return;
    int idx4 = idx * 4;
    const float* bp = bias + (idx4 & nmask);
    float4 acc = *(const float4*)bp;
    const float4* p = (const float4*)part + idx;
    for (int z = 0; z < zc; ++z) {
        float4 v = p[(size_t)z * mn4];
        acc.x += v.x; acc.y += v.y; acc.z += v.z; acc.w += v.w;
    }
    if (relu) {
        acc.x = fmaxf(acc.x, 0.f); acc.y = fmaxf(acc.y, 0.f);
        acc.z = fmaxf(acc.z, 0.f); acc.w = fmaxf(acc.w, 0.f);
    }
    if (obf) {
        ushort4 h;
        h.x = f2bf(acc.x); h.y = f2bf(acc.y); h.z = f2bf(acc.z); h.w = f2bf(acc.w);
        *(ushort4*)(obf + idx4) = h;
    }
    if (of) *(float4*)(of + idx4) = acc;
}

// ---- G2-reduce + G3 fused, wave-parallel: off = relu(red+b2) @ w3^T + b3 ---
// 1 block per roi. Phase 1: 256 threads reduce z slabs (float4 each), relu,
// -> LDS s[1024]. Phase 2: wave per output o (4 concurrent), 64 lanes split
// K=1024 as k = lane + 64*i (coalesced w3 reads, 2-way-free LDS banks),
// 16 FMA + 6-step shfl reduce.
__global__ __launch_bounds__(256) void fc_small_red(
        const float* __restrict__ part, int zc,
        const float* __restrict__ b2, const float* __restrict__ w3,
        const float* __restrict__ b3, float* __restrict__ out) {
    __shared__ float s[1024];
    int n = blockIdx.x;
    int tid = threadIdx.x;
    float4 a4 = *(const float4*)(b2 + tid * 4);
    const float* pb = part + (size_t)n * 1024 + tid * 4;
    for (int z = 0; z < zc; ++z) {
        float4 v = *(const float4*)(pb + (size_t)z * (NROI * DFC));
        a4.x += v.x; a4.y += v.y; a4.z += v.z; a4.w += v.w;
    }
    a4.x = fmaxf(a4.x, 0.f); a4.y = fmaxf(a4.y, 0.f);
    a4.z = fmaxf(a4.z, 0.f); a4.w = fmaxf(a4.w, 0.f);
    *(float4*)(s + tid * 4) = a4;
    __syncthreads();
    int wv = tid >> 6, lane = tid & 63;
    for (int o = wv; o < 98; o += 4) {
        const float* w = w3 + (size_t)o * 1024 + lane;
        float a = 0.f;
#pragma unroll
        for (int i = 0; i < 16; ++i)
            a += w[i * 64] * s[lane + i * 64];
#pragma unroll
        for (int off = 32; off > 0; off >>= 1) a += __shfl_down(a, off);
        if (lane == 0) out[n * 98 + o] = b3[o] + a;
    }
}

// ---- G5-reduce + head fused: out = relu(red(part)+fc2_b) @ box_w^T + bb ----
__global__ __launch_bounds__(64) void head_red(
        const float* __restrict__ part, int zc,
        const float* __restrict__ b4, const float* __restrict__ bw,
        const float* __restrict__ bb, float* __restrict__ out) {
    int n = blockIdx.x, t = threadIdx.x;
    float a0 = 0, a1 = 0, a2 = 0, a3 = 0;
    for (int k = t; k < 512; k += 64) {
        float acc = b4[k];
        for (int z = 0; z < zc; ++z)
            acc += part[(size_t)z * (NROI * FCC) + n * 512 + k];
        float v = fmaxf(acc, 0.f);
        a0 += v * bw[k]; a1 += v * bw[512 + k];
        a2 += v * bw[1024 + k]; a3 += v * bw[1536 + k];
    }
#pragma unroll
    for (int o = 32; o > 0; o >>= 1) {
        a0 += __shfl_down(a0, o); a1 += __shfl_down(a1, o);
        a2 += __shfl_down(a2, o); a3 += __shfl_down(a3, o);
    }
    if (t == 0) {
        out[n * 4 + 0] = a0 + bb[0]; out[n * 4 + 1] = a1 + bb[1];
        out[n * 4 + 2] = a2 + bb[2]; out[n * 4 + 3] = a3 + bb[3];
    }
}

// ---------------------------------------------------------------------------
extern "C" void kernel_launch(void* const* d_in, const int* in_sizes, int n_in,
                              void* d_out, int out_size, void* d_ws, size_t ws_size,
                              hipStream_t stream) {
    const float* x      = (const float*)d_in[0];
    const float* rois   = (const float*)d_in[1];
    const float* off_w1 = (const float*)d_in[2];
    const float* off_b1 = (const float*)d_in[3];
    const float* off_w2 = (const float*)d_in[4];
    const float* off_b2 = (const float*)d_in[5];
    const float* off_w3 = (const float*)d_in[6];
    const float* off_b3 = (const float*)d_in[7];
    const float* fc1_w  = (const float*)d_in[8];
    const float* fc1_b  = (const float*)d_in[9];
    const float* fc2_w  = (const float*)d_in[10];
    const float* fc2_b  = (const float*)d_in[11];
    const float* box_w  = (const float*)d_in[12];
    const float* box_b  = (const float*)d_in[13];
    float* out = (float*)d_out;

    char* ws = (char*)d_ws;
    size_t o = 0;
    auto carve = [&](size_t bytes) { char* p = ws + o; o += (bytes + 255) & ~(size_t)255; return p; };
    float*          xT   = (float*)carve((size_t)NB * 625 * 256 * 4);   // 5.12 MB
    unsigned short* P    = (unsigned short*)carve((size_t)NROI * INF * 2); // shared p0/p1
    unsigned short* h1b  = (unsigned short*)carve((size_t)NROI * DFC * 2);
    float*          offb = (float*)carve((size_t)NROI * 98 * 4);
    unsigned short* h3b  = (unsigned short*)carve((size_t)NROI * FCC * 2);
    size_t fixed = o;
    const size_t SLAB = (size_t)NROI * DFC * 4;   // 1 MB (G1/G2-sized slice)
    int zg1;                        // tier on ws_size (constant -> graph-safe)
    if      (ws_size >= fixed + 28 * SLAB) zg1 = 28;
    else if (ws_size >= fixed + 14 * SLAB) zg1 = 14;
    else                                   zg1 = 7;
    int zg4 = zg1 * 2;              // G4 slabs are half-size (N=512)
    float* part = (float*)carve((size_t)zg1 * SLAB);

    // 1. channels-last transpose of x
    transpose_kernel<<<dim3(20, 8, 8), 256, 0, stream>>>(x, xT);
    // 2. pool pass 0 (zero offsets), prep fused
    pool_kernel<<<dim3(2, NROI), 256, 0, stream>>>(xT, rois, nullptr, 0, P);
    // 3. G1 partials + reduce(+b1+relu) -> h1b     (256x12544x1024)
    gemm_pipe<<<dim3(16, 1, zg1), 256, 0, stream>>>(P, off_w1, part, DFC, INF, 392 / zg1);
    reduce_bias<<<256, 256, 0, stream>>>(part, zg1, NROI * DFC / 4, off_b1, DFC - 1, 1, h1b, nullptr);
    // 4. G2 partials (256x1024x1024, z=8)
    gemm_pipe<<<dim3(16, 1, 8), 256, 0, stream>>>(h1b, off_w2, part, DFC, DFC, 4);
    // 5. fused G2-reduce + G3: offb = relu(red+b2) @ w3^T + b3
    fc_small_red<<<NROI, 256, 0, stream>>>(part, 8, off_b2, off_w3, off_b3, offb);
    // 6. pool pass 1 (learned offsets), reuses P
    pool_kernel<<<dim3(2, NROI), 256, 0, stream>>>(xT, rois, offb, 1, P);
    // 7. G4 partials + reduce(+fc1_b+relu) -> h3b  (256x12544x512)
    gemm_pipe<<<dim3(8, 1, zg4), 256, 0, stream>>>(P, fc1_w, part, FCC, INF, 392 / zg4);
    reduce_bias<<<128, 256, 0, stream>>>(part, zg4, NROI * FCC / 4, fc1_b, FCC - 1, 1, h3b, nullptr);
    // 8. G5 partials (256x512x512, z=8)
    gemm_pipe<<<dim3(8, 1, 8), 256, 0, stream>>>(h3b, fc2_w, part, FCC, FCC, 2);
    // 9. fused G5-reduce + head: out = relu(red+fc2_b) @ box_w^T + box_b
    head_red<<<NROI, 64, 0, stream>>>(part, 8, fc2_b, box_w, box_b, out);
}